// Round 3
// baseline (946.159 us; speedup 1.0000x reference)
//
#include <hip/hip_runtime.h>
#include <hip/hip_fp16.h>

// ---------------------------------------------------------------------------
// MaskedGNN: 6-layer GCN.
//  z = segsum(h[src]*norm, dst) + h*dis^2 ;  h_next = relu(z @ W + b)
// Hidden state H stored fp16 (halves gather traffic); Z/GEMM/weights fp32.
// Processor layer fused: gather->LDS Z tile -> register-tiled GEMM -> fp16 out.
// CSR built on-device per call; edge records int2{src, f32 w=dis[s]*dis[d]}.
// ---------------------------------------------------------------------------

#define HW 128   // hidden width
#define BM 64    // nodes per fused-layer block
#define LPAD 130 // Z tile row pad (floats)

// ---------------- CSR build ----------------
__global__ void k_zero_i32(int* __restrict__ a, int n) {
    int i = blockIdx.x * 256 + threadIdx.x;
    if (i < n) a[i] = 0;
}

__global__ void k_hist(const int* __restrict__ dstA, int* __restrict__ deg, int e) {
    int i = blockIdx.x * 256 + threadIdx.x;
    if (i < e) atomicAdd(&deg[dstA[i]], 1);
}

__global__ void k_dis(const int* __restrict__ deg, float* __restrict__ dis, int n) {
    int i = blockIdx.x * 256 + threadIdx.x;
    if (i < n) dis[i] = rsqrtf(1.0f + (float)deg[i]);
}

__global__ void k_scan_a(const int* __restrict__ deg, int* __restrict__ tmp,
                         int* __restrict__ bsum, int n) {
    __shared__ int s[256];
    int t = threadIdx.x;
    int i = blockIdx.x * 256 + t;
    s[t] = (i < n) ? deg[i] : 0;
    __syncthreads();
    for (int off = 1; off < 256; off <<= 1) {
        int v = (t >= off) ? s[t - off] : 0;
        __syncthreads();
        s[t] += v;
        __syncthreads();
    }
    if (i < n) tmp[i] = s[t];
    if (t == 255) bsum[blockIdx.x] = s[255];
}

__global__ void k_scan_b(int* __restrict__ bsum, int nb) {
    __shared__ int s[512];
    int t = threadIdx.x;
    s[t] = (t < nb) ? bsum[t] : 0;
    __syncthreads();
    for (int off = 1; off < 512; off <<= 1) {
        int v = (t >= off) ? s[t - off] : 0;
        __syncthreads();
        s[t] += v;
        __syncthreads();
    }
    if (t < nb) bsum[t] = s[t];
}

__global__ void k_scan_c(const int* __restrict__ tmp, const int* __restrict__ deg,
                         const int* __restrict__ bsum, int* __restrict__ row_start,
                         int* __restrict__ cursor, int n, int etot) {
    int i = blockIdx.x * 256 + threadIdx.x;
    if (i < n) {
        int off = blockIdx.x ? bsum[blockIdx.x - 1] : 0;
        row_start[i] = tmp[i] - deg[i] + off;  // exclusive scan
        cursor[i] = 0;
    }
    if (i == 0) row_start[n] = etot;
}

__global__ void k_scatter(const int* __restrict__ srcA, const int* __restrict__ dstA,
                          const int* __restrict__ row_start, int* __restrict__ cursor,
                          const float* __restrict__ dis, int2* __restrict__ edata,
                          int e) {
    int i = blockIdx.x * 256 + threadIdx.x;
    if (i >= e) return;
    int d = dstA[i];
    int s = srcA[i];
    int p = atomicAdd(&cursor[d], 1);
    edata[row_start[d] + p] = make_int2(s, __float_as_int(dis[s] * dis[d]));
}

// ---------------- encoder ----------------
__global__ void k_enc_agg(const float* __restrict__ x, const int* __restrict__ rs,
                          const int2* __restrict__ edata, const float* __restrict__ dis,
                          float* __restrict__ zx, int n) {
    int i = blockIdx.x * 256 + threadIdx.x;
    if (i >= n) return;
    float di = dis[i];
    float sc = di * di;
    float a0 = x[i * 3 + 0] * sc;
    float a1 = x[i * 3 + 1] * sc;
    float a2 = x[i * 3 + 2] * sc;
    int e1 = rs[i + 1];
    for (int j = rs[i]; j < e1; ++j) {
        int2 e = edata[j];
        float w = __int_as_float(e.y);
        a0 = fmaf(w, x[e.x * 3 + 0], a0);
        a1 = fmaf(w, x[e.x * 3 + 1], a1);
        a2 = fmaf(w, x[e.x * 3 + 2], a2);
    }
    zx[i * 4 + 0] = a0;
    zx[i * 4 + 1] = a1;
    zx[i * 4 + 2] = a2;
    zx[i * 4 + 3] = 0.f;
}

__global__ void k_enc_gemm(const float* __restrict__ zx, const float* __restrict__ We,
                           const float* __restrict__ be, __half* __restrict__ H, int n) {
    int t = blockIdx.x * 256 + threadIdx.x;
    int i = t >> 7;
    int c = t & 127;
    if (i >= n) return;
    float4 z = *(const float4*)&zx[i * 4];
    float v = z.x * We[c] + z.y * We[HW + c] + z.z * We[2 * HW + c] + be[c];
    H[(size_t)i * HW + c] = __float2half_rn(fmaxf(v, 0.f));
}

// ---------------- fused processor layer ----------------
// Phase 1: each wave aggregates 16 of the block's 64 nodes into LDS Z (fp32).
//          Lane l pre-loads edge (base+l) coalesced; shfl broadcasts (src,w);
//          8-deep unroll keeps 8 fp16 row-gathers (256B each) in flight.
// Phase 2: 256-thread register-tiled fp32 GEMM Z[64][128] @ W[128][128],
//          W staged per BK=32 chunk; relu; fp16 output.
__global__ __launch_bounds__(256) void k_layer(const __half2* __restrict__ Hin,
                                               const int* __restrict__ rs,
                                               const int2* __restrict__ edata,
                                               const float* __restrict__ dis,
                                               const float* __restrict__ W,
                                               const float* __restrict__ b,
                                               __half* __restrict__ Hout, int n) {
    __shared__ float Zs[BM][LPAD];
    __shared__ float Ws[32][HW];
    int tid = threadIdx.x;
    int lane = tid & 63;
    int wave = tid >> 6;
    int blk = blockIdx.x;

    // ---- phase 1: aggregate ----
    for (int lw = wave * 16; lw < wave * 16 + 16; ++lw) {
        int g = blk * BM + lw;
        float2 acc = make_float2(0.f, 0.f);
        if (g < n) {  // wave-uniform branch
            float di = dis[g];
            float sc = di * di;
            float2 hv = __half22float2(Hin[(size_t)g * 64 + lane]);
            float2 a0 = make_float2(hv.x * sc, hv.y * sc);
            float2 a1 = make_float2(0.f, 0.f), a2 = a1, a3 = a1;
            float2 a4 = a1, a5 = a1, a6 = a1, a7 = a1;
            int e0 = rs[g], e1 = rs[g + 1];
            for (int base = e0; base < e1; base += 64) {
                int cnt = e1 - base;
                if (cnt > 64) cnt = 64;
                int myj = base + lane;
                int2 ed = (myj < e1) ? edata[myj] : make_int2(0, 0);
                int sl = ed.x;
                float wl = __int_as_float(ed.y);
                int k = 0;
                for (; k + 8 <= cnt; k += 8) {
                    int s0 = __shfl(sl, k + 0), s1 = __shfl(sl, k + 1);
                    int s2 = __shfl(sl, k + 2), s3 = __shfl(sl, k + 3);
                    int s4 = __shfl(sl, k + 4), s5 = __shfl(sl, k + 5);
                    int s6 = __shfl(sl, k + 6), s7 = __shfl(sl, k + 7);
                    float w0 = __shfl(wl, k + 0), w1 = __shfl(wl, k + 1);
                    float w2 = __shfl(wl, k + 2), w3 = __shfl(wl, k + 3);
                    float w4 = __shfl(wl, k + 4), w5 = __shfl(wl, k + 5);
                    float w6 = __shfl(wl, k + 6), w7 = __shfl(wl, k + 7);
                    __half2 g0 = Hin[(size_t)s0 * 64 + lane];
                    __half2 g1 = Hin[(size_t)s1 * 64 + lane];
                    __half2 g2 = Hin[(size_t)s2 * 64 + lane];
                    __half2 g3 = Hin[(size_t)s3 * 64 + lane];
                    __half2 g4 = Hin[(size_t)s4 * 64 + lane];
                    __half2 g5 = Hin[(size_t)s5 * 64 + lane];
                    __half2 g6 = Hin[(size_t)s6 * 64 + lane];
                    __half2 g7 = Hin[(size_t)s7 * 64 + lane];
                    float2 v0 = __half22float2(g0), v1 = __half22float2(g1);
                    float2 v2 = __half22float2(g2), v3 = __half22float2(g3);
                    float2 v4 = __half22float2(g4), v5 = __half22float2(g5);
                    float2 v6 = __half22float2(g6), v7 = __half22float2(g7);
                    a0.x = fmaf(w0, v0.x, a0.x); a0.y = fmaf(w0, v0.y, a0.y);
                    a1.x = fmaf(w1, v1.x, a1.x); a1.y = fmaf(w1, v1.y, a1.y);
                    a2.x = fmaf(w2, v2.x, a2.x); a2.y = fmaf(w2, v2.y, a2.y);
                    a3.x = fmaf(w3, v3.x, a3.x); a3.y = fmaf(w3, v3.y, a3.y);
                    a4.x = fmaf(w4, v4.x, a4.x); a4.y = fmaf(w4, v4.y, a4.y);
                    a5.x = fmaf(w5, v5.x, a5.x); a5.y = fmaf(w5, v5.y, a5.y);
                    a6.x = fmaf(w6, v6.x, a6.x); a6.y = fmaf(w6, v6.y, a6.y);
                    a7.x = fmaf(w7, v7.x, a7.x); a7.y = fmaf(w7, v7.y, a7.y);
                }
                for (; k < cnt; ++k) {
                    int s = __shfl(sl, k);
                    float w = __shfl(wl, k);
                    float2 v = __half22float2(Hin[(size_t)s * 64 + lane]);
                    a0.x = fmaf(w, v.x, a0.x); a0.y = fmaf(w, v.y, a0.y);
                }
            }
            acc.x = ((a0.x + a1.x) + (a2.x + a3.x)) + ((a4.x + a5.x) + (a6.x + a7.x));
            acc.y = ((a0.y + a1.y) + (a2.y + a3.y)) + ((a4.y + a5.y) + (a6.y + a7.y));
        }
        Zs[lw][2 * lane] = acc.x;
        Zs[lw][2 * lane + 1] = acc.y;
    }

    // ---- phase 2: GEMM ----
    int tx = tid & 15;   // col group: cols tx*8..tx*8+7
    int ty = tid >> 4;   // row group: rows ty*4..ty*4+3
    float acc2[4][8];
#pragma unroll
    for (int i = 0; i < 4; ++i)
#pragma unroll
        for (int j = 0; j < 8; ++j) acc2[i][j] = 0.f;

    for (int kc = 0; kc < HW; kc += 32) {
        __syncthreads();  // first iter: phase1 done; later: prev chunk consumed
#pragma unroll
        for (int i = 0; i < 4; ++i) {
            int q = tid + i * 256;  // float4 id 0..1023
            int r = q >> 5, c4 = q & 31;
            *(float4*)&Ws[r][c4 * 4] = *(const float4*)&W[(size_t)(kc + r) * HW + c4 * 4];
        }
        __syncthreads();
#pragma unroll 8
        for (int k = 0; k < 32; ++k) {
            float zr[4];
#pragma unroll
            for (int i = 0; i < 4; ++i) zr[i] = Zs[ty * 4 + i][kc + k];
            float4 w0 = *(const float4*)&Ws[k][tx * 8];
            float4 w1 = *(const float4*)&Ws[k][tx * 8 + 4];
            float wr[8] = {w0.x, w0.y, w0.z, w0.w, w1.x, w1.y, w1.z, w1.w};
#pragma unroll
            for (int i = 0; i < 4; ++i)
#pragma unroll
                for (int j = 0; j < 8; ++j)
                    acc2[i][j] = fmaf(zr[i], wr[j], acc2[i][j]);
        }
    }

    float br[8];
#pragma unroll
    for (int j = 0; j < 8; ++j) br[j] = b[tx * 8 + j];
#pragma unroll
    for (int i = 0; i < 4; ++i) {
        int grow = blk * BM + ty * 4 + i;
        if (grow < n) {
            union { uint4 u; __half2 h[4]; } pk;
#pragma unroll
            for (int j = 0; j < 4; ++j) {
                float lo = fmaxf(acc2[i][2 * j] + br[2 * j], 0.f);
                float hi = fmaxf(acc2[i][2 * j + 1] + br[2 * j + 1], 0.f);
                pk.h[j] = __floats2half2_rn(lo, hi);
            }
            *(uint4*)&Hout[(size_t)grow * HW + tx * 8] = pk.u;
        }
    }
}

// ---------------- decoder ----------------
__global__ __launch_bounds__(256) void k_dec_mv(const __half2* __restrict__ H,
                                                const float* __restrict__ Wd,
                                                float* __restrict__ t, int n) {
    int node = blockIdx.x * 4 + (threadIdx.x >> 6);
    int lane = threadIdx.x & 63;
    if (node >= n) return;
    float2 h = __half22float2(H[(size_t)node * 64 + lane]);
    float2 w = ((const float2*)Wd)[lane];
    float s = h.x * w.x + h.y * w.y;
    for (int off = 32; off; off >>= 1) s += __shfl_down(s, off);
    if (lane == 0) t[node] = s;
}

__global__ void k_dec_out(const float* __restrict__ t, const int* __restrict__ rs,
                          const int2* __restrict__ edata, const float* __restrict__ dis,
                          const float* __restrict__ bdec, const float* __restrict__ mask,
                          float* __restrict__ out, int n) {
    int i = blockIdx.x * 256 + threadIdx.x;
    if (i >= n) return;
    float di = dis[i];
    float acc = t[i] * di * di;
    int e1 = rs[i + 1];
    for (int j = rs[i]; j < e1; ++j) {
        int2 e = edata[j];
        acc = fmaf(__int_as_float(e.y), t[e.x], acc);
    }
    out[i] = (acc + bdec[0]) * mask[i];
}

// ---------------------------------------------------------------------------
static inline size_t align256(size_t x) { return (x + 255) & ~(size_t)255; }

extern "C" void kernel_launch(void* const* d_in, const int* in_sizes, int n_in,
                              void* d_out, int out_size, void* d_ws, size_t ws_size,
                              hipStream_t stream) {
    const float* x     = (const float*)d_in[0];
    const float* mask  = (const float*)d_in[1];
    const int*   ei    = (const int*)d_in[2];
    const float* W_enc = (const float*)d_in[3];
    const float* b_enc = (const float*)d_in[4];
    const float* W_p   = (const float*)d_in[5];
    const float* b_p   = (const float*)d_in[6];
    const float* W_dec = (const float*)d_in[7];
    const float* b_dec = (const float*)d_in[8];

    const int N = in_sizes[1];
    const int E = in_sizes[2] / 2;
    const int* srcA = ei;
    const int* dstA = ei + E;

    char* p = (char*)d_ws;
    size_t off = 0;
    auto carve = [&](size_t bytes) {
        void* r = p + off;
        off += align256(bytes);
        return r;
    };
    int*    deg       = (int*)carve((size_t)N * 4);
    int*    cursor    = (int*)carve((size_t)N * 4);
    int*    row_start = (int*)carve((size_t)(N + 1) * 4);
    int*    bsum      = (int*)carve(512 * 4);
    int2*   edata     = (int2*)carve((size_t)E * 8);
    float*  dis       = (float*)carve((size_t)N * 4);
    float*  zx        = (float*)carve((size_t)N * 4 * 4);  // also scan tmp
    float*  tdec      = (float*)carve((size_t)N * 4);
    __half* HA        = (__half*)carve((size_t)N * HW * 2);
    __half* HB        = (__half*)carve((size_t)N * HW * 2);
    int*    tmp       = (int*)zx;

    const int gN   = (N + 255) / 256;
    const int gE   = (E + 255) / 256;
    const int gNd4 = (N + 3) / 4;
    const int gL   = (N + BM - 1) / BM;

    // ---- CSR build ----
    k_zero_i32<<<gN, 256, 0, stream>>>(deg, N);
    k_hist<<<gE, 256, 0, stream>>>(dstA, deg, E);
    k_dis<<<gN, 256, 0, stream>>>(deg, dis, N);
    k_scan_a<<<gN, 256, 0, stream>>>(deg, tmp, bsum, N);
    k_scan_b<<<1, 512, 0, stream>>>(bsum, gN);
    k_scan_c<<<gN, 256, 0, stream>>>(tmp, deg, bsum, row_start, cursor, N, E);
    k_scatter<<<gE, 256, 0, stream>>>(srcA, dstA, row_start, cursor, dis, edata, E);

    // ---- encoder ----
    k_enc_agg<<<gN, 256, 0, stream>>>(x, row_start, edata, dis, zx, N);
    k_enc_gemm<<<(N * HW + 255) / 256, 256, 0, stream>>>(zx, W_enc, b_enc, HA, N);

    // ---- 4 fused processor layers (ping-pong HA/HB) ----
    __half* Hin = HA;
    __half* Hout = HB;
    for (int l = 0; l < 4; ++l) {
        k_layer<<<gL, 256, 0, stream>>>((const __half2*)Hin, row_start, edata, dis,
                                        W_p + (size_t)l * HW * HW, b_p + (size_t)l * HW,
                                        Hout, N);
        __half* t = Hin; Hin = Hout; Hout = t;
    }

    // ---- decoder ----
    k_dec_mv<<<gNd4, 256, 0, stream>>>((const __half2*)Hin, W_dec, tdec, N);
    k_dec_out<<<gN, 256, 0, stream>>>(tdec, row_start, edata, dis, b_dec, mask,
                                      (float*)d_out, N);
}

// Round 4
// 711.865 us; speedup vs baseline: 1.3291x; 1.3291x over previous
//
#include <hip/hip_runtime.h>
#include <hip/hip_fp16.h>

// ---------------------------------------------------------------------------
// MaskedGNN: 6-layer GCN.
//  z = segsum(h[src]*norm, dst) + h*dis^2 ;  h_next = relu(z @ W + b)
// H and Z stored fp16 (halves gather traffic). Aggregation standalone at full
// occupancy (R2 structure). Processor GEMM via MFMA f32_16x16x32_f16, W split
// hi/lo fp16 (W effectively exact), fp32 accumulate, in-place on the H buffer.
// CSR built on-device per call; edge records int2{src, f32 w=dis[s]*dis[d]}.
// ---------------------------------------------------------------------------

#define HW 128  // hidden width

typedef _Float16 f16x8 __attribute__((ext_vector_type(8)));
typedef float f32x4 __attribute__((ext_vector_type(4)));

// ---------------- CSR build ----------------
__global__ void k_zero_i32(int* __restrict__ a, int n) {
    int i = blockIdx.x * 256 + threadIdx.x;
    if (i < n) a[i] = 0;
}

__global__ void k_hist(const int* __restrict__ dstA, int* __restrict__ deg, int e) {
    int i = blockIdx.x * 256 + threadIdx.x;
    if (i < e) atomicAdd(&deg[dstA[i]], 1);
}

__global__ void k_dis(const int* __restrict__ deg, float* __restrict__ dis, int n) {
    int i = blockIdx.x * 256 + threadIdx.x;
    if (i < n) dis[i] = rsqrtf(1.0f + (float)deg[i]);
}

__global__ void k_scan_a(const int* __restrict__ deg, int* __restrict__ tmp,
                         int* __restrict__ bsum, int n) {
    __shared__ int s[256];
    int t = threadIdx.x;
    int i = blockIdx.x * 256 + t;
    s[t] = (i < n) ? deg[i] : 0;
    __syncthreads();
    for (int off = 1; off < 256; off <<= 1) {
        int v = (t >= off) ? s[t - off] : 0;
        __syncthreads();
        s[t] += v;
        __syncthreads();
    }
    if (i < n) tmp[i] = s[t];
    if (t == 255) bsum[blockIdx.x] = s[255];
}

__global__ void k_scan_b(int* __restrict__ bsum, int nb) {
    __shared__ int s[512];
    int t = threadIdx.x;
    s[t] = (t < nb) ? bsum[t] : 0;
    __syncthreads();
    for (int off = 1; off < 512; off <<= 1) {
        int v = (t >= off) ? s[t - off] : 0;
        __syncthreads();
        s[t] += v;
        __syncthreads();
    }
    if (t < nb) bsum[t] = s[t];
}

__global__ void k_scan_c(const int* __restrict__ tmp, const int* __restrict__ deg,
                         const int* __restrict__ bsum, int* __restrict__ row_start,
                         int* __restrict__ cursor, int n, int etot) {
    int i = blockIdx.x * 256 + threadIdx.x;
    if (i < n) {
        int off = blockIdx.x ? bsum[blockIdx.x - 1] : 0;
        row_start[i] = tmp[i] - deg[i] + off;  // exclusive scan
        cursor[i] = 0;
    }
    if (i == 0) row_start[n] = etot;
}

__global__ void k_scatter(const int* __restrict__ srcA, const int* __restrict__ dstA,
                          const int* __restrict__ row_start, int* __restrict__ cursor,
                          const float* __restrict__ dis, int2* __restrict__ edata,
                          int e) {
    int i = blockIdx.x * 256 + threadIdx.x;
    if (i >= e) return;
    int d = dstA[i];
    int s = srcA[i];
    int p = atomicAdd(&cursor[d], 1);
    edata[row_start[d] + p] = make_int2(s, __float_as_int(dis[s] * dis[d]));
}

// ---------------- W prep: transpose + hi/lo fp16 split ----------------
// WTh/WTl[l][col][k] = fp16 split of W_p[l][k][col]
__global__ void k_prep_wt(const float* __restrict__ Wp, __half* __restrict__ WTh,
                          __half* __restrict__ WTl, int total) {
    int t = blockIdx.x * 256 + threadIdx.x;
    if (t >= total) return;
    int l = t >> 14;
    int kc = t & 16383;
    int k = kc >> 7, c = kc & 127;
    float w = Wp[t];
    __half hi = __float2half_rn(w);
    __half lo = __float2half_rn(w - __half2float(hi));
    size_t o = ((size_t)l << 14) + (size_t)c * HW + k;
    WTh[o] = hi;
    WTl[o] = lo;
}

// ---------------- encoder ----------------
__global__ void k_enc_agg(const float* __restrict__ x, const int* __restrict__ rs,
                          const int2* __restrict__ edata, const float* __restrict__ dis,
                          float* __restrict__ zx, int n) {
    int i = blockIdx.x * 256 + threadIdx.x;
    if (i >= n) return;
    float di = dis[i];
    float sc = di * di;
    float a0 = x[i * 3 + 0] * sc;
    float a1 = x[i * 3 + 1] * sc;
    float a2 = x[i * 3 + 2] * sc;
    int e1 = rs[i + 1];
    for (int j = rs[i]; j < e1; ++j) {
        int2 e = edata[j];
        float w = __int_as_float(e.y);
        a0 = fmaf(w, x[e.x * 3 + 0], a0);
        a1 = fmaf(w, x[e.x * 3 + 1], a1);
        a2 = fmaf(w, x[e.x * 3 + 2], a2);
    }
    zx[i * 4 + 0] = a0;
    zx[i * 4 + 1] = a1;
    zx[i * 4 + 2] = a2;
    zx[i * 4 + 3] = 0.f;
}

__global__ void k_enc_gemm(const float* __restrict__ zx, const float* __restrict__ We,
                           const float* __restrict__ be, __half* __restrict__ H, int n) {
    int t = blockIdx.x * 256 + threadIdx.x;
    int i = t >> 7;
    int c = t & 127;
    if (i >= n) return;
    float4 z = *(const float4*)&zx[i * 4];
    float v = z.x * We[c] + z.y * We[HW + c] + z.z * We[2 * HW + c] + be[c];
    H[(size_t)i * HW + c] = __float2half_rn(fmaxf(v, 0.f));
}

// ---------------- width-128 aggregate: one wave per node, fp16 ----------------
// Lane l pre-loads edge (base+l) coalesced; shfl broadcasts (src, w).
// 8 independent accumulators keep 8 gathers of 256B in flight per wave.
__global__ __launch_bounds__(256) void k_agg128(const __half2* __restrict__ Hin,
                                                const int* __restrict__ rs,
                                                const int2* __restrict__ edata,
                                                const float* __restrict__ dis,
                                                __half2* __restrict__ Z, int n) {
    int node = blockIdx.x * 4 + (threadIdx.x >> 6);
    int lane = threadIdx.x & 63;
    if (node >= n) return;
    float di = dis[node];
    float2 hv = __half22float2(Hin[(size_t)node * 64 + lane]);
    float sc = di * di;
    float2 a0 = make_float2(hv.x * sc, hv.y * sc);
    float2 a1 = make_float2(0.f, 0.f), a2 = a1, a3 = a1;
    float2 a4 = a1, a5 = a1, a6 = a1, a7 = a1;
    int e0 = rs[node], e1 = rs[node + 1];
    for (int base = e0; base < e1; base += 64) {
        int cnt = e1 - base;
        if (cnt > 64) cnt = 64;
        int myj = base + lane;
        int2 ed = (myj < e1) ? edata[myj] : make_int2(0, 0);
        int sl = ed.x;
        float wl = __int_as_float(ed.y);
        int k = 0;
        for (; k + 8 <= cnt; k += 8) {
            int s0 = __shfl(sl, k + 0), s1 = __shfl(sl, k + 1);
            int s2 = __shfl(sl, k + 2), s3 = __shfl(sl, k + 3);
            int s4 = __shfl(sl, k + 4), s5 = __shfl(sl, k + 5);
            int s6 = __shfl(sl, k + 6), s7 = __shfl(sl, k + 7);
            float w0 = __shfl(wl, k + 0), w1 = __shfl(wl, k + 1);
            float w2 = __shfl(wl, k + 2), w3 = __shfl(wl, k + 3);
            float w4 = __shfl(wl, k + 4), w5 = __shfl(wl, k + 5);
            float w6 = __shfl(wl, k + 6), w7 = __shfl(wl, k + 7);
            __half2 g0 = Hin[(size_t)s0 * 64 + lane];
            __half2 g1 = Hin[(size_t)s1 * 64 + lane];
            __half2 g2 = Hin[(size_t)s2 * 64 + lane];
            __half2 g3 = Hin[(size_t)s3 * 64 + lane];
            __half2 g4 = Hin[(size_t)s4 * 64 + lane];
            __half2 g5 = Hin[(size_t)s5 * 64 + lane];
            __half2 g6 = Hin[(size_t)s6 * 64 + lane];
            __half2 g7 = Hin[(size_t)s7 * 64 + lane];
            float2 v0 = __half22float2(g0), v1 = __half22float2(g1);
            float2 v2 = __half22float2(g2), v3 = __half22float2(g3);
            float2 v4 = __half22float2(g4), v5 = __half22float2(g5);
            float2 v6 = __half22float2(g6), v7 = __half22float2(g7);
            a0.x = fmaf(w0, v0.x, a0.x); a0.y = fmaf(w0, v0.y, a0.y);
            a1.x = fmaf(w1, v1.x, a1.x); a1.y = fmaf(w1, v1.y, a1.y);
            a2.x = fmaf(w2, v2.x, a2.x); a2.y = fmaf(w2, v2.y, a2.y);
            a3.x = fmaf(w3, v3.x, a3.x); a3.y = fmaf(w3, v3.y, a3.y);
            a4.x = fmaf(w4, v4.x, a4.x); a4.y = fmaf(w4, v4.y, a4.y);
            a5.x = fmaf(w5, v5.x, a5.x); a5.y = fmaf(w5, v5.y, a5.y);
            a6.x = fmaf(w6, v6.x, a6.x); a6.y = fmaf(w6, v6.y, a6.y);
            a7.x = fmaf(w7, v7.x, a7.x); a7.y = fmaf(w7, v7.y, a7.y);
        }
        for (; k < cnt; ++k) {
            int s = __shfl(sl, k);
            float w = __shfl(wl, k);
            float2 v = __half22float2(Hin[(size_t)s * 64 + lane]);
            a0.x = fmaf(w, v.x, a0.x); a0.y = fmaf(w, v.y, a0.y);
        }
    }
    float2 acc;
    acc.x = ((a0.x + a1.x) + (a2.x + a3.x)) + ((a4.x + a5.x) + (a6.x + a7.x));
    acc.y = ((a0.y + a1.y) + (a2.y + a3.y)) + ((a4.y + a5.y) + (a6.y + a7.y));
    Z[(size_t)node * 64 + lane] = __floats2half2_rn(acc.x, acc.y);
}

// ---------------- MFMA GEMM: H = relu(Z @ W + b), in place (Z == H buffer) ---
// 256 threads = 4 waves; block owns 256 rows, wave owns 64 rows x 128 cols.
// A-frags from global Z (fp16); B-frags from global WT hi/lo (L2-resident).
// Layout (16x16x32): A row=lane&15, k=(lane>>4)*8+j ; B col=lane&15, same k;
// C/D col=lane&15, row=(lane>>4)*4+reg  [verified m89].
#define GBM 256
__global__ __launch_bounds__(256) void k_gemm_mfma(const __half* __restrict__ Z,
                                                   const __half* __restrict__ WTh,
                                                   const __half* __restrict__ WTl,
                                                   const float* __restrict__ b,
                                                   __half* __restrict__ Hout, int n) {
    int wave = threadIdx.x >> 6, lane = threadIdx.x & 63;
    int q = lane >> 4, r16 = lane & 15;
    int row0 = blockIdx.x * GBM + wave * 64;

    f32x4 acc[4][8];
#pragma unroll
    for (int mt = 0; mt < 4; ++mt)
#pragma unroll
        for (int nt = 0; nt < 8; ++nt) acc[mt][nt] = (f32x4)0.f;

#pragma unroll
    for (int ks = 0; ks < 4; ++ks) {
        f16x8 afr[4];
#pragma unroll
        for (int mt = 0; mt < 4; ++mt) {
            int row = row0 + mt * 16 + r16;
            row = row < n ? row : (n - 1);  // clamp; results discarded at store
            afr[mt] = *(const f16x8*)(Z + (size_t)row * HW + ks * 32 + q * 8);
        }
#pragma unroll
        for (int nt = 0; nt < 8; ++nt) {
            f16x8 bh = *(const f16x8*)(WTh + (size_t)(nt * 16 + r16) * HW + ks * 32 + q * 8);
            f16x8 bl = *(const f16x8*)(WTl + (size_t)(nt * 16 + r16) * HW + ks * 32 + q * 8);
#pragma unroll
            for (int mt = 0; mt < 4; ++mt) {
                acc[mt][nt] = __builtin_amdgcn_mfma_f32_16x16x32_f16(afr[mt], bh, acc[mt][nt], 0, 0, 0);
                acc[mt][nt] = __builtin_amdgcn_mfma_f32_16x16x32_f16(afr[mt], bl, acc[mt][nt], 0, 0, 0);
            }
        }
    }

#pragma unroll
    for (int nt = 0; nt < 8; ++nt) {
        float bias = b[nt * 16 + r16];
#pragma unroll
        for (int mt = 0; mt < 4; ++mt) {
#pragma unroll
            for (int r = 0; r < 4; ++r) {
                int row = row0 + mt * 16 + q * 4 + r;
                if (row < n) {
                    float v = fmaxf(acc[mt][nt][r] + bias, 0.f);
                    Hout[(size_t)row * HW + nt * 16 + r16] = __float2half_rn(v);
                }
            }
        }
    }
}

// ---------------- decoder ----------------
__global__ __launch_bounds__(256) void k_dec_mv(const __half2* __restrict__ H,
                                                const float* __restrict__ Wd,
                                                float* __restrict__ t, int n) {
    int node = blockIdx.x * 4 + (threadIdx.x >> 6);
    int lane = threadIdx.x & 63;
    if (node >= n) return;
    float2 h = __half22float2(H[(size_t)node * 64 + lane]);
    float2 w = ((const float2*)Wd)[lane];
    float s = h.x * w.x + h.y * w.y;
    for (int off = 32; off; off >>= 1) s += __shfl_down(s, off);
    if (lane == 0) t[node] = s;
}

__global__ void k_dec_out(const float* __restrict__ t, const int* __restrict__ rs,
                          const int2* __restrict__ edata, const float* __restrict__ dis,
                          const float* __restrict__ bdec, const float* __restrict__ mask,
                          float* __restrict__ out, int n) {
    int i = blockIdx.x * 256 + threadIdx.x;
    if (i >= n) return;
    float di = dis[i];
    float acc = t[i] * di * di;
    int e1 = rs[i + 1];
    for (int j = rs[i]; j < e1; ++j) {
        int2 e = edata[j];
        acc = fmaf(__int_as_float(e.y), t[e.x], acc);
    }
    out[i] = (acc + bdec[0]) * mask[i];
}

// ---------------------------------------------------------------------------
static inline size_t align256(size_t x) { return (x + 255) & ~(size_t)255; }

extern "C" void kernel_launch(void* const* d_in, const int* in_sizes, int n_in,
                              void* d_out, int out_size, void* d_ws, size_t ws_size,
                              hipStream_t stream) {
    const float* x     = (const float*)d_in[0];
    const float* mask  = (const float*)d_in[1];
    const int*   ei    = (const int*)d_in[2];
    const float* W_enc = (const float*)d_in[3];
    const float* b_enc = (const float*)d_in[4];
    const float* W_p   = (const float*)d_in[5];
    const float* b_p   = (const float*)d_in[6];
    const float* W_dec = (const float*)d_in[7];
    const float* b_dec = (const float*)d_in[8];

    const int N = in_sizes[1];
    const int E = in_sizes[2] / 2;
    const int* srcA = ei;
    const int* dstA = ei + E;

    char* p = (char*)d_ws;
    size_t off = 0;
    auto carve = [&](size_t bytes) {
        void* r = p + off;
        off += align256(bytes);
        return r;
    };
    int*    deg       = (int*)carve((size_t)N * 4);
    int*    cursor    = (int*)carve((size_t)N * 4);
    int*    row_start = (int*)carve((size_t)(N + 1) * 4);
    int*    bsum      = (int*)carve(512 * 4);
    int2*   edata     = (int2*)carve((size_t)E * 8);
    float*  dis       = (float*)carve((size_t)N * 4);
    float*  zx        = (float*)carve((size_t)N * 4 * 4);  // also scan tmp
    float*  tdec      = (float*)carve((size_t)N * 4);
    __half* WTh       = (__half*)carve((size_t)4 * HW * HW * 2);
    __half* WTl       = (__half*)carve((size_t)4 * HW * HW * 2);
    __half* HA        = (__half*)carve((size_t)N * HW * 2);
    __half* HB        = (__half*)carve((size_t)N * HW * 2);
    int*    tmp       = (int*)zx;

    const int gN   = (N + 255) / 256;
    const int gE   = (E + 255) / 256;
    const int gNd4 = (N + 3) / 4;
    const int gG   = (N + GBM - 1) / GBM;
    const int WPT  = 4 * HW * HW;

    // ---- CSR build + W prep ----
    k_zero_i32<<<gN, 256, 0, stream>>>(deg, N);
    k_hist<<<gE, 256, 0, stream>>>(dstA, deg, E);
    k_dis<<<gN, 256, 0, stream>>>(deg, dis, N);
    k_scan_a<<<gN, 256, 0, stream>>>(deg, tmp, bsum, N);
    k_scan_b<<<1, 512, 0, stream>>>(bsum, gN);
    k_scan_c<<<gN, 256, 0, stream>>>(tmp, deg, bsum, row_start, cursor, N, E);
    k_scatter<<<gE, 256, 0, stream>>>(srcA, dstA, row_start, cursor, dis, edata, E);
    k_prep_wt<<<(WPT + 255) / 256, 256, 0, stream>>>(W_p, WTh, WTl, WPT);

    // ---- encoder ----
    k_enc_agg<<<gN, 256, 0, stream>>>(x, row_start, edata, dis, zx, N);
    k_enc_gemm<<<(N * HW + 255) / 256, 256, 0, stream>>>(zx, W_enc, b_enc, HA, N);

    // ---- 4 processor layers: agg(Hin->Hother), gemm in place on Hother ----
    __half* Hin = HA;
    __half* Hoth = HB;
    for (int l = 0; l < 4; ++l) {
        k_agg128<<<gNd4, 256, 0, stream>>>((const __half2*)Hin, row_start, edata, dis,
                                           (__half2*)Hoth, N);
        k_gemm_mfma<<<gG, 256, 0, stream>>>(Hoth, WTh + (size_t)l * HW * HW,
                                            WTl + (size_t)l * HW * HW,
                                            b_p + (size_t)l * HW, Hoth, N);
        __half* t = Hin; Hin = Hoth; Hoth = t;
    }

    // ---- decoder ----
    k_dec_mv<<<gNd4, 256, 0, stream>>>((const __half2*)Hin, W_dec, tdec, N);
    k_dec_out<<<gN, 256, 0, stream>>>(tdec, row_start, edata, dis, b_dec, mask,
                                      (float*)d_out, N);
}